// Round 6
// baseline (85.661 us; speedup 1.0000x reference)
//
#include <hip/hip_runtime.h>

// NCC loss (B=2, C=1, 160^3 f32, 9^3 box window).
// pass_z : products + sliding z-window sums -> fp8(e4m3) bufA, layout
//          [b][z][y][field][x] (800 B per (z,y) row-group).
// pass_yx: sliding y-window in f32 registers + x-window via wave shuffles
//          (20 lanes = 1 row-tuple, 3 tuples/wave) + cc + reduction.
//          CHY=2 + launch_bounds(,5) for occupancy/latency hiding.
// finalize: deterministic reduce of block partials.

typedef float floatx2 __attribute__((ext_vector_type(2)));

constexpr int W = 160, H = 160, D = 160;
constexpr int SLICE = W * H;           // 25600
constexpr int NVOX  = W * H * D;       // 4,096,000
constexpr int BATCH = 2;
constexpr int FROW  = 5 * W;           // 800 fp8 bytes per (z,y) row-group
constexpr float RW  = 1.0f / 729.0f;

// pass_z geometry
constexpr int TPB_Z = 256;
constexpr int XG4   = W / 4;                     // 40 groups of 4 x
constexpr int CHZ   = 5, NCHZ = D / CHZ;         // 32 z-chunks
constexpr int NTH_Z = BATCH * XG4 * H * NCHZ;    // 409,600
constexpr int NBLK_Z = NTH_Z / TPB_Z;            // 1600

// pass_yx geometry
constexpr int TPB_YX = 256;
constexpr int XG  = W / 8;                       // 20 lanes per row-tuple
constexpr int CHY = 2, NCHY = H / CHY;           // 80 y-chunks
constexpr int NTUP = BATCH * D * NCHY;           // 25,600 tuples
constexpr int TPW  = 3;                          // tuples per wave
constexpr int TPBLK = 4 * TPW;                   // 12 tuples per block
constexpr int NBLK_YX = (NTUP + TPBLK - 1) / TPBLK;  // 2134

// ---- fp8 helpers (HW cvt, OCP e4m3 on gfx950) ----------------------------
__device__ inline unsigned int pk4(float a, float b, float c, float d) {
    unsigned int u = 0;
    u = __builtin_amdgcn_cvt_pk_fp8_f32(a, b, u, false);  // bytes 0,1
    u = __builtin_amdgcn_cvt_pk_fp8_f32(c, d, u, true);   // bytes 2,3
    return u;
}
__device__ inline void up8(uint2 v, float* o) {
    floatx2 t;
    t = __builtin_amdgcn_cvt_pk_f32_fp8(v.x, false); o[0] = t[0]; o[1] = t[1];
    t = __builtin_amdgcn_cvt_pk_f32_fp8(v.x, true);  o[2] = t[0]; o[3] = t[1];
    t = __builtin_amdgcn_cvt_pk_f32_fp8(v.y, false); o[4] = t[0]; o[5] = t[1];
    t = __builtin_amdgcn_cvt_pk_f32_fp8(v.y, true);  o[6] = t[0]; o[7] = t[1];
}

// ---- pass 1: products + sliding window-sum along z -----------------------
__global__ __launch_bounds__(TPB_Z) void pass_z(const float* __restrict__ I,
                                                const float* __restrict__ J,
                                                unsigned char* __restrict__ outA) {
    int t = blockIdx.x * TPB_Z + threadIdx.x;
    int xg = t % XG4;
    int y  = (t / XG4) % H;
    int c  = (t / (XG4 * H)) % NCHZ;
    int b  = t / (XG4 * H * NCHZ);
    int x0 = xg * 4;
    const float* Ib = I + (size_t)b * NVOX + y * W + x0;
    const float* Jb = J + (size_t)b * NVOX + y * W + x0;
    unsigned char* ob = outA + ((size_t)b * D * H + y) * FROW + x0;

    float s[5][4];
#pragma unroll
    for (int f = 0; f < 5; ++f)
#pragma unroll
        for (int i = 0; i < 4; ++i) s[f][i] = 0.f;

    auto addS = [&](int zz) {
        float4 a = *(const float4*)(Ib + (size_t)zz * SLICE);
        float4 bb = *(const float4*)(Jb + (size_t)zz * SLICE);
        float av[4] = {a.x, a.y, a.z, a.w};
        float bv[4] = {bb.x, bb.y, bb.z, bb.w};
#pragma unroll
        for (int i = 0; i < 4; ++i) {
            float x = av[i], yv = bv[i];
            s[0][i] += x; s[1][i] += yv;
            s[2][i] += x * x; s[3][i] += yv * yv; s[4][i] += x * yv;
        }
    };

    int z0 = c * CHZ;
    for (int zz = (z0 - 4 < 0 ? 0 : z0 - 4); zz <= z0 + 4; ++zz) addS(zz);

#pragma unroll
    for (int dz = 0; dz < CHZ; ++dz) {
        int z = z0 + dz;
        int za = z + 5, zs = z - 4;
        bool ha = za < D, hs = zs >= 0;
        float4 Az = ha ? *(const float4*)(Ib + (size_t)za * SLICE) : make_float4(0.f, 0.f, 0.f, 0.f);
        float4 Bz = ha ? *(const float4*)(Jb + (size_t)za * SLICE) : make_float4(0.f, 0.f, 0.f, 0.f);
        float4 As = hs ? *(const float4*)(Ib + (size_t)zs * SLICE) : make_float4(0.f, 0.f, 0.f, 0.f);
        float4 Bs = hs ? *(const float4*)(Jb + (size_t)zs * SLICE) : make_float4(0.f, 0.f, 0.f, 0.f);

        unsigned char* op = ob + (size_t)z * (H * FROW);
#pragma unroll
        for (int f = 0; f < 5; ++f)
            *(unsigned int*)(op + f * W) = pk4(s[f][0], s[f][1], s[f][2], s[f][3]);

        float ae[4] = {Az.x, Az.y, Az.z, Az.w};
        float be[4] = {Bz.x, Bz.y, Bz.z, Bz.w};
        float al[4] = {As.x, As.y, As.z, As.w};
        float bl[4] = {Bs.x, Bs.y, Bs.z, Bs.w};
#pragma unroll
        for (int i = 0; i < 4; ++i) {
            s[0][i] += ae[i] - al[i];
            s[1][i] += be[i] - bl[i];
            s[2][i] += ae[i] * ae[i] - al[i] * al[i];
            s[3][i] += be[i] * be[i] - bl[i] * bl[i];
            s[4][i] += ae[i] * be[i] - al[i] * bl[i];
        }
    }
}

// ---- pass 2: y-window (regs) + x-window (shuffles) + cc + reduce ---------
__global__ __launch_bounds__(TPB_YX, 5) void pass_yx(const unsigned char* __restrict__ A,
                                                     double* __restrict__ partials) {
    int tid = threadIdx.x;
    int lane = tid & 63, wvi = tid >> 6;
    int g = lane / XG, xg = lane % XG;          // g==3 -> idle lanes 60..63
    int tuple = blockIdx.x * TPBLK + wvi * TPW + g;
    bool valid = (g < TPW) && (tuple < NTUP);
    int t = valid ? tuple : 0;
    int yc = t % NCHY;
    int z  = (t / NCHY) % D;
    int b  = t / (NCHY * D);
    int x0 = xg * 8;
    const unsigned char* __restrict__ base =
        A + (size_t)(b * D + z) * H * FROW + x0;
    int y0 = yc * CHY;

    float s[5][8];
#pragma unroll
    for (int f = 0; f < 5; ++f)
#pragma unroll
        for (int i = 0; i < 8; ++i) s[f][i] = 0.f;

    // initial y-window: rows y0-4 .. y0+4 (clamped)
    int ylo = y0 - 4 < 0 ? 0 : y0 - 4;
    int yhi = y0 + 4 > H - 1 ? H - 1 : y0 + 4;
    for (int yy = ylo; yy <= yhi; ++yy) {
        const unsigned char* rp = base + (size_t)yy * FROW;
#pragma unroll
        for (int f = 0; f < 5; ++f) {
            uint2 v = *(const uint2*)(rp + f * W);
            float u[8]; up8(v, u);
#pragma unroll
            for (int i = 0; i < 8; ++i) s[f][i] += u[i];
        }
    }

    double acc = 0.0;
#pragma unroll
    for (int dy = 0; dy < CHY; ++dy) {
        int ye = y0 + dy + 5, yl = y0 + dy - 4;
        bool he = ye < H, hl = yl >= 0;
        uint2 pe[5], pl[5];
        const unsigned char* pre = base + (size_t)(he ? ye : 0) * FROW;
        const unsigned char* prl = base + (size_t)(hl ? yl : 0) * FROW;
#pragma unroll
        for (int f = 0; f < 5; ++f) {
            pe[f] = he ? *(const uint2*)(pre + f * W) : make_uint2(0u, 0u);
            pl[f] = hl ? *(const uint2*)(prl + f * W) : make_uint2(0u, 0u);
        }

        // x-window sums from current s via prefix + neighbor-lane shuffles
        float wv5[5][8];
#pragma unroll
        for (int f = 0; f < 5; ++f) {
            float p0 = s[f][0];
            float p1 = p0 + s[f][1];
            float p2 = p1 + s[f][2];
            float p3 = p2 + s[f][3];
            float p4 = p3 + s[f][4];
            float p5 = p4 + s[f][5];
            float p6 = p5 + s[f][6];
            float tot = p6 + s[f][7];
            float a0 = tot - p3, a1 = tot - p4, a2 = tot - p5, a3 = tot - p6;
            float L0 = __shfl_up(a0, 1), L1 = __shfl_up(a1, 1);
            float L2 = __shfl_up(a2, 1), L3 = __shfl_up(a3, 1);
            float R0 = __shfl_down(p0, 1), R1 = __shfl_down(p1, 1);
            float R2 = __shfl_down(p2, 1), R3 = __shfl_down(p3, 1);
            if (xg == 0)      { L0 = 0.f; L1 = 0.f; L2 = 0.f; L3 = 0.f; }
            if (xg == XG - 1) { R0 = 0.f; R1 = 0.f; R2 = 0.f; R3 = 0.f; }
            wv5[f][0] = L0 + p4;
            wv5[f][1] = L1 + p5;
            wv5[f][2] = L2 + p6;
            wv5[f][3] = L3 + tot;
            wv5[f][4] = tot + R0;
            wv5[f][5] = (tot - p0) + R1;
            wv5[f][6] = (tot - p1) + R2;
            wv5[f][7] = (tot - p2) + R3;
        }

        float rowcc = 0.f;
#pragma unroll
        for (int i = 0; i < 8; ++i) {
            float Is = wv5[0][i], Js = wv5[1][i];
            float I2s = wv5[2][i], J2s = wv5[3][i], IJs = wv5[4][i];
            float tI = RW * Is;
            float cross = __builtin_fmaf(-tI, Js, IJs);       // IJs - Is*Js/729
            float Iv    = __builtin_fmaf(-tI, Is, I2s);       // I2s - Is^2/729
            float Jv    = __builtin_fmaf(-(RW * Js), Js, J2s);
            float den   = __builtin_fmaf(Iv, Jv, 1e-5f);
            rowcc = __builtin_fmaf(cross * cross, __builtin_amdgcn_rcpf(den), rowcc);
        }
        acc += (double)rowcc;

        // slide the y-window
#pragma unroll
        for (int f = 0; f < 5; ++f) {
            float ue[8], ul[8];
            up8(pe[f], ue); up8(pl[f], ul);
#pragma unroll
            for (int i = 0; i < 8; ++i) s[f][i] += ue[i] - ul[i];
        }
    }

    if (!valid) acc = 0.0;

    // deterministic block reduction
#pragma unroll
    for (int off = 32; off > 0; off >>= 1) acc += __shfl_down(acc, off);
    __shared__ double sm[TPB_YX / 64];
    if ((tid & 63) == 0) sm[tid >> 6] = acc;
    __syncthreads();
    if (tid == 0) {
        double tt = 0.0;
#pragma unroll
        for (int i = 0; i < TPB_YX / 64; ++i) tt += sm[i];
        partials[blockIdx.x] = tt;
    }
}

// ---- final deterministic reduce ------------------------------------------
__global__ __launch_bounds__(256) void finalize(const double* __restrict__ p,
                                                float* __restrict__ out) {
    double v = 0.0;
    for (int i = threadIdx.x; i < NBLK_YX; i += 256) v += p[i];
#pragma unroll
    for (int off = 32; off > 0; off >>= 1) v += __shfl_down(v, off);
    __shared__ double sm[4];
    int lane = threadIdx.x & 63, wid = threadIdx.x >> 6;
    if (lane == 0) sm[wid] = v;
    __syncthreads();
    if (threadIdx.x == 0) {
        double tt = 0.0;
#pragma unroll
        for (int i = 0; i < 4; ++i) tt += sm[i];
        out[0] = (float)(1.0 - tt / (double)((double)BATCH * (double)NVOX));
    }
}

extern "C" void kernel_launch(void* const* d_in, const int* in_sizes, int n_in,
                              void* d_out, int out_size, void* d_ws, size_t ws_size,
                              hipStream_t stream) {
    const float* I = (const float*)d_in[0];
    const float* J = (const float*)d_in[1];
    float* out = (float*)d_out;

    // ws layout: bufA (BATCH*5*NVOX fp8 bytes = 41 MB) | partials (NBLK_YX f64)
    unsigned char* bufA = (unsigned char*)d_ws;
    double* partials = (double*)(bufA + ((size_t)BATCH * 5 * NVOX + 255) / 256 * 256);

    pass_z<<<NBLK_Z, TPB_Z, 0, stream>>>(I, J, bufA);
    pass_yx<<<NBLK_YX, TPB_YX, 0, stream>>>(bufA, partials);
    finalize<<<1, 256, 0, stream>>>(partials, out);
}